// Round 1
// baseline (231.577 us; speedup 1.0000x reference)
//
#include <hip/hip_runtime.h>
#include <math.h>

#define BB 32
#define LL 128
#define HH 512
#define MM 512
#define KT 32
#define LP (LL + 4)   // padded LDS leading dim
#define EPSF 1e-8f

// ws layout (floats):
//   [0, 524288)        Cx  [32][128][128]
//   [524288, 524320)   normsqx[32]
//   [524320, 524832)   normsqy[512]
//   [524832, 541216)   hsic[32][512]
#define WS_CX      0
#define WS_NSQX    524288
#define WS_NSQY    524320
#define WS_HSIC    524832

// Computes C = (H A)(H A)^T for one matrix A (L x H), where H A subtracts the
// per-column (over L) mean. FUSE=0: write C to Cout, normsq. FUSE=1: keep C in
// registers, write normsq, and write hsic[b][blockIdx.x] = <C, Cx[b]> for all b.
template<int FUSE>
__global__ __launch_bounds__(256)
void gram_kernel(const float* __restrict__ Aall,
                 float* __restrict__ Cout,
                 float* __restrict__ normsq,
                 const float* __restrict__ Cx,
                 float* __restrict__ hsic)
{
    __shared__ float ldsT[KT][LP];     // [k][l], centered in-place
    __shared__ float partial[8][KT];
    __shared__ float kmean[KT];
    __shared__ float red[256];
    __shared__ float warr[BB * 4];

    const int tid = threadIdx.x;
    const int tx = tid & 15, ty = tid >> 4;
    const int i0 = ty * 8, j0 = tx * 8;
    const int n = blockIdx.x;
    const float* Amat = Aall + (size_t)n * LL * HH;

    float acc[8][8];
#pragma unroll
    for (int r = 0; r < 8; ++r)
#pragma unroll
        for (int c = 0; c < 8; ++c) acc[r][c] = 0.f;

    const int lld = tid >> 3;   // 0..31
    const int k4  = tid & 7;    // float4 column within tile

    for (int k0 = 0; k0 < HH; k0 += KT) {
        // ---- load 128 x 32 tile, transposed into ldsT[k][l] ----
#pragma unroll
        for (int ch = 0; ch < 4; ++ch) {
            const int l = lld + ch * 32;
            const float4 v = *reinterpret_cast<const float4*>(
                Amat + (size_t)l * HH + k0 + k4 * 4);
            ldsT[k4 * 4 + 0][l] = v.x;
            ldsT[k4 * 4 + 1][l] = v.y;
            ldsT[k4 * 4 + 2][l] = v.z;
            ldsT[k4 * 4 + 3][l] = v.w;
        }
        __syncthreads();
        // ---- per-k (column of A) mean over l ----
        {
            const int c = tid & 31, seg = tid >> 5;
            float s = 0.f;
#pragma unroll
            for (int q = 0; q < 16; ++q) s += ldsT[c][seg * 16 + q];
            partial[seg][c] = s;
        }
        __syncthreads();
        if (tid < KT) {
            float s = 0.f;
#pragma unroll
            for (int q = 0; q < 8; ++q) s += partial[q][tid];
            kmean[tid] = s * (1.f / LL);
        }
        __syncthreads();
        // ---- subtract means in place (center the columns) ----
        {
            const int base = tid * 16;
#pragma unroll
            for (int q = 0; q < 16; ++q) {
                const int idx = base + q;
                const int k = idx >> 7, l = idx & 127;
                ldsT[k][l] -= kmean[k];
            }
        }
        __syncthreads();
        // ---- outer-product accumulate ----
#pragma unroll
        for (int k = 0; k < KT; ++k) {
            float ar[8], ac[8];
#pragma unroll
            for (int r = 0; r < 8; ++r) ar[r] = ldsT[k][i0 + r];
#pragma unroll
            for (int c = 0; c < 8; ++c) ac[c] = ldsT[k][j0 + c];
#pragma unroll
            for (int r = 0; r < 8; ++r)
#pragma unroll
                for (int c = 0; c < 8; ++c)
                    acc[r][c] = fmaf(ar[r], ac[c], acc[r][c]);
        }
        __syncthreads();
    }

    // ---- Frobenius norm^2 of C ----
    {
        float nsq = 0.f;
#pragma unroll
        for (int r = 0; r < 8; ++r)
#pragma unroll
            for (int c = 0; c < 8; ++c) nsq = fmaf(acc[r][c], acc[r][c], nsq);
        red[tid] = nsq;
        __syncthreads();
        for (int s = 128; s > 0; s >>= 1) {
            if (tid < s) red[tid] += red[tid + s];
            __syncthreads();
        }
        if (tid == 0) normsq[n] = red[0];
    }

    if (FUSE == 0) {
        float* Cb = Cout + (size_t)n * LL * LL;
#pragma unroll
        for (int r = 0; r < 8; ++r) {
            float4 v0 = make_float4(acc[r][0], acc[r][1], acc[r][2], acc[r][3]);
            float4 v1 = make_float4(acc[r][4], acc[r][5], acc[r][6], acc[r][7]);
            *reinterpret_cast<float4*>(Cb + (size_t)(i0 + r) * LL + j0)     = v0;
            *reinterpret_cast<float4*>(Cb + (size_t)(i0 + r) * LL + j0 + 4) = v1;
        }
    } else {
        const int wid = tid >> 6, lane = tid & 63;
        for (int b = 0; b < BB; ++b) {
            const float* Cb = Cx + (size_t)b * LL * LL;
            float p = 0.f;
#pragma unroll
            for (int r = 0; r < 8; ++r) {
                const float4 u0 = *reinterpret_cast<const float4*>(
                    Cb + (size_t)(i0 + r) * LL + j0);
                const float4 u1 = *reinterpret_cast<const float4*>(
                    Cb + (size_t)(i0 + r) * LL + j0 + 4);
                p = fmaf(acc[r][0], u0.x, p);
                p = fmaf(acc[r][1], u0.y, p);
                p = fmaf(acc[r][2], u0.z, p);
                p = fmaf(acc[r][3], u0.w, p);
                p = fmaf(acc[r][4], u1.x, p);
                p = fmaf(acc[r][5], u1.y, p);
                p = fmaf(acc[r][6], u1.z, p);
                p = fmaf(acc[r][7], u1.w, p);
            }
#pragma unroll
            for (int off = 32; off > 0; off >>= 1) p += __shfl_down(p, off, 64);
            if (lane == 0) warr[b * 4 + wid] = p;
        }
        __syncthreads();
        if (tid < BB) {
            const float s = warr[tid * 4] + warr[tid * 4 + 1] +
                            warr[tid * 4 + 2] + warr[tid * 4 + 3];
            hsic[(size_t)tid * MM + n] = s;
        }
    }
}

__global__ __launch_bounds__(512)
void finalize_kernel(const float* __restrict__ normsqx,
                     const float* __restrict__ normsqy,
                     const float* __restrict__ hsic,
                     float* __restrict__ out)
{
    __shared__ float vx[BB];
    __shared__ float vy[MM];
    __shared__ int   ids[BB];
    __shared__ float rsum[512];

    const int tid = threadIdx.x;
    if (tid < BB) vx[tid] = sqrtf(normsqx[tid]);
    vy[tid] = sqrtf(normsqy[tid]);
    __syncthreads();

    // loss matrix -> out[1..B*M]
    for (int i = tid; i < BB * MM; i += 512) {
        const int b = i >> 9, m = i & 511;
        const float ratio = fabsf(hsic[i]) / (vx[b] * vy[m]);
        out[1 + i] = -logf(ratio + EPSF);
    }
    __syncthreads();

    // argmax per row (first occurrence on ties, matching jnp.argmax)
    const int wid = tid >> 6, lane = tid & 63;
    for (int b = wid; b < BB; b += 8) {
        float best = -INFINITY;
        int bm = 0;
        for (int m = lane; m < MM; m += 64) {
            const float ratio = fabsf(hsic[b * MM + m]) / (vx[b] * vy[m]);
            const float v = -logf(ratio + EPSF);
            if (v > best) { best = v; bm = m; }   // strict > keeps earliest m
        }
#pragma unroll
        for (int off = 32; off > 0; off >>= 1) {
            const float ov = __shfl_down(best, off, 64);
            const int   om = __shfl_down(bm, off, 64);
            if (ov > best || (ov == best && om < bm)) { best = ov; bm = om; }
        }
        if (lane == 0) {
            ids[b] = bm;
            out[1 + BB * MM + b] = (float)bm;
        }
    }
    __syncthreads();

    // scalar loss: mean over (b,c) of |hsic[b, idx[c]]| / (vx[b]*vy[idx[c]])
    float s = 0.f;
    for (int i = tid; i < BB * BB; i += 512) {
        const int b = i >> 5, c = i & 31;
        const int m = ids[c];
        s += fabsf(hsic[(size_t)b * MM + m]) / (vx[b] * vy[m]);
    }
    rsum[tid] = s;
    __syncthreads();
    for (int t = 256; t > 0; t >>= 1) {
        if (tid < t) rsum[tid] += rsum[tid + t];
        __syncthreads();
    }
    if (tid == 0) out[0] = -logf(rsum[0] * (1.f / (BB * BB)) + EPSF);
}

extern "C" void kernel_launch(void* const* d_in, const int* in_sizes, int n_in,
                              void* d_out, int out_size, void* d_ws, size_t ws_size,
                              hipStream_t stream) {
    const float* x    = (const float*)d_in[0];   // (32,128,512)
    const float* cent = (const float*)d_in[1];   // (512, 128*512)
    float* out = (float*)d_out;
    float* ws  = (float*)d_ws;

    float* Cx      = ws + WS_CX;
    float* normsqx = ws + WS_NSQX;
    float* normsqy = ws + WS_NSQY;
    float* hsic    = ws + WS_HSIC;

    // 1) centered Grams of x -> Cx, normsqx
    gram_kernel<0><<<BB, 256, 0, stream>>>(x, Cx, normsqx, nullptr, nullptr);
    // 2) centered Grams of centroids (registers only) + fused hsic vs all Cx
    gram_kernel<1><<<MM, 256, 0, stream>>>(cent, nullptr, normsqy, Cx, hsic);
    // 3) loss matrix, argmax, scalar loss
    finalize_kernel<<<1, 512, 0, stream>>>(normsqx, normsqy, hsic, out);
}

// Round 2
// 125.988 us; speedup vs baseline: 1.8381x; 1.8381x over previous
//
#include <hip/hip_runtime.h>
#include <math.h>

#define BB 32
#define LL 128
#define HH 512
#define MM 512
#define EPSF 1e-8f

// ws layout (floats):
//   [0, 524288)        Cx (permuted fragment layout) [32][4 wave][16 tile][64 lane][4]
//   [524288, 524320)   normsqx[32]
//   [524320, 524832)   normsqy[512]
//   [524832, 541216)   hsic[32][512]
#define WS_CX      0
#define WS_NSQX    524288
#define WS_NSQY    524320
#define WS_HSIC    524832

typedef __attribute__((ext_vector_type(8))) short short8b;  // 8 bf16 (4 VGPRs)
typedef __attribute__((ext_vector_type(4))) float f32x4;    // MFMA accum

// One block per matrix A (128x512). Centers columns (over L), splits each
// centered f32 exactly into 3 truncated-bf16 planes (c = a0+a1+a2), and
// accumulates C = (HA)(HA)^T with 6 MFMA passes (00,01,10,11,02,20) per
// k-slice -> f32-equivalent accuracy at MFMA rates.
// FUSE=0: write C in fragment-permuted layout + normsq.
// FUSE=1: keep C in regs, write normsq and hsic[b][n] = <C, Cx_b> for all b.
template<int FUSE>
__global__ __launch_bounds__(256, 2)
void gram_mfma(const float* __restrict__ Aall,
               float* __restrict__ Cout,
               float* __restrict__ normsq,
               const float* __restrict__ Cxp,
               float* __restrict__ hsic)
{
    // [plane][k-slot(8 bf16)][row] of 16B entries: A/B frag = one b128 read
    __shared__ short8b planes[3][4][128];     // 24 KB
    __shared__ float colpart[32][32];         // 4 KB  [rowgroup][k]
    __shared__ float kmean[32];
    __shared__ float red[256];
    __shared__ float warr[BB * 4];

    const int tid  = threadIdx.x;
    const int lane = tid & 63;
    const int wid  = tid >> 6;              // 4 waves
    const int qi   = (wid >> 1) * 64;       // quadrant rows
    const int qj   = (wid & 1) * 64;        // quadrant cols
    const int n    = blockIdx.x;
    const float* Amat = Aall + (size_t)n * LL * HH;

    const int rg = tid >> 3;                // row group 0..31 (rows rg+32p)
    const int kb = tid & 7;                 // k-quad (4 floats) within 32-k tile

    f32x4 acc[4][4];
#pragma unroll
    for (int i = 0; i < 4; ++i)
#pragma unroll
        for (int j = 0; j < 4; ++j)
            acc[i][j] = (f32x4){0.f, 0.f, 0.f, 0.f};

    uint2* P2 = (uint2*)planes;             // 8B view: [(pl*4+slot)*128+r]*2+half

    // prefetch K-tile 0
    float4 v[4];
#pragma unroll
    for (int p = 0; p < 4; ++p)
        v[p] = *(const float4*)(Amat + (size_t)(rg + 32 * p) * HH + kb * 4);

    for (int t = 0; t < 16; ++t) {
        // prefetch next K-tile (redundant reload of tile 15 on last iter)
        float4 vn[4];
        const int k0n = (t < 15) ? (t + 1) * 32 : 480;
#pragma unroll
        for (int p = 0; p < 4; ++p)
            vn[p] = *(const float4*)(Amat + (size_t)(rg + 32 * p) * HH + k0n + kb * 4);

        // ---- per-k column partial sums (this thread's 4 rows) ----
        float4 cp;
        cp.x = v[0].x + v[1].x + v[2].x + v[3].x;
        cp.y = v[0].y + v[1].y + v[2].y + v[3].y;
        cp.z = v[0].z + v[1].z + v[2].z + v[3].z;
        cp.w = v[0].w + v[1].w + v[2].w + v[3].w;
        *(float4*)&colpart[rg][kb * 4] = cp;
        __syncthreads();                                   // S1
        if (tid < 32) {
            float s = 0.f;
#pragma unroll
            for (int g = 0; g < 32; ++g) s += colpart[g][tid];
            kmean[tid] = s * (1.f / LL);
        }
        __syncthreads();                                   // S2

        // ---- center + exact 3-plane bf16 split + plane writes ----
        const float mu0 = kmean[kb * 4 + 0];
        const float mu1 = kmean[kb * 4 + 1];
        const float mu2 = kmean[kb * 4 + 2];
        const float mu3 = kmean[kb * 4 + 3];
#pragma unroll
        for (int p = 0; p < 4; ++p) {
            const int r = rg + 32 * p;
            const float c0 = v[p].x - mu0;
            const float c1 = v[p].y - mu1;
            const float c2 = v[p].z - mu2;
            const float c3 = v[p].w - mu3;

            const unsigned int h0 = __float_as_uint(c0) & 0xffff0000u;
            const unsigned int h1 = __float_as_uint(c1) & 0xffff0000u;
            const unsigned int h2 = __float_as_uint(c2) & 0xffff0000u;
            const unsigned int h3 = __float_as_uint(c3) & 0xffff0000u;
            const float r10 = c0 - __uint_as_float(h0);
            const float r11 = c1 - __uint_as_float(h1);
            const float r12 = c2 - __uint_as_float(h2);
            const float r13 = c3 - __uint_as_float(h3);
            const unsigned int m0 = __float_as_uint(r10) & 0xffff0000u;
            const unsigned int m1 = __float_as_uint(r11) & 0xffff0000u;
            const unsigned int m2 = __float_as_uint(r12) & 0xffff0000u;
            const unsigned int m3 = __float_as_uint(r13) & 0xffff0000u;
            const unsigned int l0 = __float_as_uint(r10 - __uint_as_float(m0));
            const unsigned int l1 = __float_as_uint(r11 - __uint_as_float(m1));
            const unsigned int l2 = __float_as_uint(r12 - __uint_as_float(m2));
            const unsigned int l3 = __float_as_uint(r13 - __uint_as_float(m3));

            uint2 w0, w1, w2;
            w0.x = (h0 >> 16) | h1;                  w0.y = (h2 >> 16) | h3;
            w1.x = (m0 >> 16) | m1;                  w1.y = (m2 >> 16) | m3;
            w2.x = (l0 >> 16) | (l1 & 0xffff0000u);  w2.y = (l2 >> 16) | (l3 & 0xffff0000u);

            const int u2 = (((kb >> 1)) * 128 + r) * 2 + (kb & 1);
            P2[u2]        = w0;    // plane 0 (stride 4*128*2 = 1024 uint2)
            P2[u2 + 1024] = w1;    // plane 1
            P2[u2 + 2048] = w2;    // plane 2
        }
        __syncthreads();                                   // S3

        // ---- MFMA: 16 16x16 tiles per wave, 6 passes each ----
        {
            const int s = lane >> 4;
            const int lr = lane & 15;
            short8b af0[4], af1[4], af2[4];
#pragma unroll
            for (int i = 0; i < 4; ++i) {
                const int r = qi + i * 16 + lr;
                af0[i] = planes[0][s][r];
                af1[i] = planes[1][s][r];
                af2[i] = planes[2][s][r];
            }
#pragma unroll
            for (int j = 0; j < 4; ++j) {
                const int r = qj + j * 16 + lr;
                const short8b b0 = planes[0][s][r];
                const short8b b1 = planes[1][s][r];
                const short8b b2 = planes[2][s][r];
#pragma unroll
                for (int i = 0; i < 4; ++i) {
                    acc[i][j] = __builtin_amdgcn_mfma_f32_16x16x32_bf16(af0[i], b0, acc[i][j], 0, 0, 0);
                    acc[i][j] = __builtin_amdgcn_mfma_f32_16x16x32_bf16(af0[i], b1, acc[i][j], 0, 0, 0);
                    acc[i][j] = __builtin_amdgcn_mfma_f32_16x16x32_bf16(af1[i], b0, acc[i][j], 0, 0, 0);
                    acc[i][j] = __builtin_amdgcn_mfma_f32_16x16x32_bf16(af1[i], b1, acc[i][j], 0, 0, 0);
                    acc[i][j] = __builtin_amdgcn_mfma_f32_16x16x32_bf16(af0[i], b2, acc[i][j], 0, 0, 0);
                    acc[i][j] = __builtin_amdgcn_mfma_f32_16x16x32_bf16(af2[i], b0, acc[i][j], 0, 0, 0);
                }
            }
        }
        // no sync needed here: next iter's S1+S2 precede the next plane write
#pragma unroll
        for (int p = 0; p < 4; ++p) v[p] = vn[p];
    }

    // ---- ||C||_F^2 ----
    {
        float nsq = 0.f;
#pragma unroll
        for (int i = 0; i < 4; ++i)
#pragma unroll
            for (int j = 0; j < 4; ++j)
#pragma unroll
                for (int q = 0; q < 4; ++q)
                    nsq = fmaf(acc[i][j][q], acc[i][j][q], nsq);
        red[tid] = nsq;
        __syncthreads();
        for (int s = 128; s > 0; s >>= 1) {
            if (tid < s) red[tid] += red[tid + s];
            __syncthreads();
        }
        if (tid == 0) normsq[n] = red[0];
    }

    if (FUSE == 0) {
        // fragment-permuted store: [(n*4+wid)*16 + tile]*256 + lane*4
#pragma unroll
        for (int i = 0; i < 4; ++i)
#pragma unroll
            for (int j = 0; j < 4; ++j) {
                const int t = i * 4 + j;
                float* dst = Cout + (((size_t)n * 4 + wid) * 16 + t) * 256 + lane * 4;
                *(f32x4*)dst = acc[i][j];
            }
    } else {
        // hsic[b][n] = <C, Cx_b>; Cx stored in the same fragment layout so
        // each lane reads exactly its own fragment: coalesced 16B/lane.
        for (int b = 0; b < BB; ++b) {
            const float* Cb = Cxp + ((size_t)b * 4 + wid) * 4096 + lane * 4;
            float p = 0.f;
#pragma unroll
            for (int t = 0; t < 16; ++t) {
                const f32x4 u = *(const f32x4*)(Cb + t * 256);
                const int i = t >> 2, j = t & 3;
                p = fmaf(u[0], acc[i][j][0], p);
                p = fmaf(u[1], acc[i][j][1], p);
                p = fmaf(u[2], acc[i][j][2], p);
                p = fmaf(u[3], acc[i][j][3], p);
            }
#pragma unroll
            for (int off = 32; off > 0; off >>= 1) p += __shfl_down(p, off, 64);
            if (lane == 0) warr[b * 4 + wid] = p;
        }
        __syncthreads();
        if (tid < BB) {
            hsic[(size_t)tid * MM + n] = warr[tid * 4] + warr[tid * 4 + 1] +
                                         warr[tid * 4 + 2] + warr[tid * 4 + 3];
        }
    }
}

__global__ __launch_bounds__(512)
void finalize_kernel(const float* __restrict__ normsqx,
                     const float* __restrict__ normsqy,
                     const float* __restrict__ hsic,
                     float* __restrict__ out)
{
    __shared__ float vx[BB];
    __shared__ float vy[MM];
    __shared__ int   ids[BB];
    __shared__ float rsum[512];

    const int tid = threadIdx.x;
    if (tid < BB) vx[tid] = sqrtf(normsqx[tid]);
    vy[tid] = sqrtf(normsqy[tid]);
    __syncthreads();

    // loss matrix -> out[1..B*M]
    for (int i = tid; i < BB * MM; i += 512) {
        const int b = i >> 9, m = i & 511;
        const float ratio = fabsf(hsic[i]) / (vx[b] * vy[m]);
        out[1 + i] = -logf(ratio + EPSF);
    }
    __syncthreads();

    // argmax per row (first occurrence on ties, matching jnp.argmax)
    const int wid = tid >> 6, lane = tid & 63;
    for (int b = wid; b < BB; b += 8) {
        float best = -INFINITY;
        int bm = 0;
        for (int m = lane; m < MM; m += 64) {
            const float ratio = fabsf(hsic[b * MM + m]) / (vx[b] * vy[m]);
            const float v = -logf(ratio + EPSF);
            if (v > best) { best = v; bm = m; }
        }
#pragma unroll
        for (int off = 32; off > 0; off >>= 1) {
            const float ov = __shfl_down(best, off, 64);
            const int   om = __shfl_down(bm, off, 64);
            if (ov > best || (ov == best && om < bm)) { best = ov; bm = om; }
        }
        if (lane == 0) {
            ids[b] = bm;
            out[1 + BB * MM + b] = (float)bm;
        }
    }
    __syncthreads();

    // scalar loss: mean over (b,c) of |hsic[b, idx[c]]| / (vx[b]*vy[idx[c]])
    float s = 0.f;
    for (int i = tid; i < BB * BB; i += 512) {
        const int b = i >> 5, c = i & 31;
        const int m = ids[c];
        s += fabsf(hsic[(size_t)b * MM + m]) / (vx[b] * vy[m]);
    }
    rsum[tid] = s;
    __syncthreads();
    for (int t = 256; t > 0; t >>= 1) {
        if (tid < t) rsum[tid] += rsum[tid + t];
        __syncthreads();
    }
    if (tid == 0) out[0] = -logf(rsum[0] * (1.f / (BB * BB)) + EPSF);
}

extern "C" void kernel_launch(void* const* d_in, const int* in_sizes, int n_in,
                              void* d_out, int out_size, void* d_ws, size_t ws_size,
                              hipStream_t stream) {
    const float* x    = (const float*)d_in[0];   // (32,128,512)
    const float* cent = (const float*)d_in[1];   // (512, 128*512)
    float* out = (float*)d_out;
    float* ws  = (float*)d_ws;

    float* Cx      = ws + WS_CX;
    float* normsqx = ws + WS_NSQX;
    float* normsqy = ws + WS_NSQY;
    float* hsic    = ws + WS_HSIC;

    // 1) centered Grams of x -> Cx (fragment layout), normsqx
    gram_mfma<0><<<BB, 256, 0, stream>>>(x, Cx, normsqx, nullptr, nullptr);
    // 2) centered Grams of centroids (registers only) + fused hsic vs all Cx
    gram_mfma<1><<<MM, 256, 0, stream>>>(cent, nullptr, normsqy, Cx, hsic);
    // 3) loss matrix, argmax, scalar loss
    finalize_kernel<<<1, 512, 0, stream>>>(normsqx, normsqy, hsic, out);
}

// Round 3
// 114.149 us; speedup vs baseline: 2.0287x; 1.1037x over previous
//
#include <hip/hip_runtime.h>
#include <math.h>

#define BB 32
#define LL 128
#define HH 512
#define MM 512
#define NM 544          // 32 x-matrices + 512 centroids
#define EPSF 1e-8f

typedef __attribute__((ext_vector_type(8))) short short8b;  // 8 bf16
typedef __attribute__((ext_vector_type(4))) float f32x4;

// ---------------- new-path ws layout (floats) ----------------
//   Cp     [544][16384]          @ 0
//   part   [64][32][512]         @ 8912896
//   normsq [544]                 @ 9961472
//   hsic   [32][512]             @ 9962016
//   ids    [32] (int)            @ 9978400
#define NWS_CP     0
#define NWS_PART   8912896
#define NWS_NSQ    9961472
#define NWS_HSIC   9962016
#define NWS_IDS    9978400
#define NWS_BYTES  (9978432UL * 4UL)

// =====================================================================
// K1: raw Gram via 3-plane bf16 MFMA, then double-center in registers.
// One block per matrix (544 blocks). Writes centered C (f32, fragment-
// permuted flat order) and ||C||_F^2.
// =====================================================================
__global__ __launch_bounds__(256, 2)
void gram_center_store(const float* __restrict__ x,
                       const float* __restrict__ cent,
                       float* __restrict__ Cp,
                       float* __restrict__ normsq)
{
    __shared__ short8b planes[2][3][4][128];   // double-buffered, 48 KB
    __shared__ float rowpart[2][128];
    __shared__ float rmv[128];
    __shared__ float red[256];
    __shared__ float gmsh;

    const int tid  = threadIdx.x;
    const int lane = tid & 63;
    const int wid  = tid >> 6;
    const int qi   = (wid >> 1) * 64;
    const int qj   = (wid & 1) * 64;
    const int n    = blockIdx.x;
    const float* Amat = (n < BB) ? (x + (size_t)n * LL * HH)
                                 : (cent + (size_t)(n - BB) * LL * HH);

    const int rg = tid >> 3;    // 0..31 (rows rg+32p)
    const int kb = tid & 7;     // k-quad within 32-k tile

    f32x4 acc[4][4];
#pragma unroll
    for (int i = 0; i < 4; ++i)
#pragma unroll
        for (int j = 0; j < 4; ++j) acc[i][j] = (f32x4){0.f, 0.f, 0.f, 0.f};

    float4 v[4];
#pragma unroll
    for (int p = 0; p < 4; ++p)
        v[p] = *(const float4*)(Amat + (size_t)(rg + 32 * p) * HH + kb * 4);

    for (int t = 0; t < 16; ++t) {
        const int pb = t & 1;
        // prefetch next K-tile
        float4 vn[4];
        const int k0n = (t < 15) ? (t + 1) * 32 : 480;
#pragma unroll
        for (int p = 0; p < 4; ++p)
            vn[p] = *(const float4*)(Amat + (size_t)(rg + 32 * p) * HH + k0n + kb * 4);

        // exact 3-plane split of raw values, write to LDS
        uint2* P2 = (uint2*)planes[pb];
#pragma unroll
        for (int p = 0; p < 4; ++p) {
            const int r = rg + 32 * p;
            const float c0 = v[p].x, c1 = v[p].y, c2 = v[p].z, c3 = v[p].w;
            const unsigned int h0 = __float_as_uint(c0) & 0xffff0000u;
            const unsigned int h1 = __float_as_uint(c1) & 0xffff0000u;
            const unsigned int h2 = __float_as_uint(c2) & 0xffff0000u;
            const unsigned int h3 = __float_as_uint(c3) & 0xffff0000u;
            const float r10 = c0 - __uint_as_float(h0);
            const float r11 = c1 - __uint_as_float(h1);
            const float r12 = c2 - __uint_as_float(h2);
            const float r13 = c3 - __uint_as_float(h3);
            const unsigned int m0 = __float_as_uint(r10) & 0xffff0000u;
            const unsigned int m1 = __float_as_uint(r11) & 0xffff0000u;
            const unsigned int m2 = __float_as_uint(r12) & 0xffff0000u;
            const unsigned int m3 = __float_as_uint(r13) & 0xffff0000u;
            const unsigned int l0 = __float_as_uint(r10 - __uint_as_float(m0));
            const unsigned int l1 = __float_as_uint(r11 - __uint_as_float(m1));
            const unsigned int l2 = __float_as_uint(r12 - __uint_as_float(m2));
            const unsigned int l3 = __float_as_uint(r13 - __uint_as_float(m3));
            uint2 w0, w1, w2;
            w0.x = (h0 >> 16) | h1;                  w0.y = (h2 >> 16) | h3;
            w1.x = (m0 >> 16) | m1;                  w1.y = (m2 >> 16) | m3;
            w2.x = (l0 >> 16) | (l1 & 0xffff0000u);  w2.y = (l2 >> 16) | (l3 & 0xffff0000u);
            const int u2 = ((kb >> 1) * 128 + r) * 2 + (kb & 1);
            P2[u2]        = w0;
            P2[u2 + 1024] = w1;
            P2[u2 + 2048] = w2;
        }
        __syncthreads();

        // MFMA: 6 passes (hh,hm,mh,mm,hl,lh) per 16x16 tile
        {
            const int s = lane >> 4, lr = lane & 15;
            short8b af0[4], af1[4], af2[4];
#pragma unroll
            for (int i = 0; i < 4; ++i) {
                const int r = qi + i * 16 + lr;
                af0[i] = planes[pb][0][s][r];
                af1[i] = planes[pb][1][s][r];
                af2[i] = planes[pb][2][s][r];
            }
#pragma unroll
            for (int j = 0; j < 4; ++j) {
                const int r = qj + j * 16 + lr;
                const short8b b0 = planes[pb][0][s][r];
                const short8b b1 = planes[pb][1][s][r];
                const short8b b2 = planes[pb][2][s][r];
#pragma unroll
                for (int i = 0; i < 4; ++i) {
                    acc[i][j] = __builtin_amdgcn_mfma_f32_16x16x32_bf16(af0[i], b0, acc[i][j], 0, 0, 0);
                    acc[i][j] = __builtin_amdgcn_mfma_f32_16x16x32_bf16(af0[i], b1, acc[i][j], 0, 0, 0);
                    acc[i][j] = __builtin_amdgcn_mfma_f32_16x16x32_bf16(af1[i], b0, acc[i][j], 0, 0, 0);
                    acc[i][j] = __builtin_amdgcn_mfma_f32_16x16x32_bf16(af1[i], b1, acc[i][j], 0, 0, 0);
                    acc[i][j] = __builtin_amdgcn_mfma_f32_16x16x32_bf16(af0[i], b2, acc[i][j], 0, 0, 0);
                    acc[i][j] = __builtin_amdgcn_mfma_f32_16x16x32_bf16(af2[i], b0, acc[i][j], 0, 0, 0);
                }
            }
        }
#pragma unroll
        for (int p = 0; p < 4; ++p) v[p] = vn[p];
    }

    // ---- double-centering: C = G - rm_i - rm_j + gm ----
    // per-lane partial row sums over this wave's 64 cols
#pragma unroll
    for (int i = 0; i < 4; ++i)
#pragma unroll
        for (int q = 0; q < 4; ++q) {
            float s = acc[i][0][q] + acc[i][1][q] + acc[i][2][q] + acc[i][3][q];
            s += __shfl_xor(s, 1, 64);
            s += __shfl_xor(s, 2, 64);
            s += __shfl_xor(s, 4, 64);
            s += __shfl_xor(s, 8, 64);
            if ((lane & 15) == 0)
                rowpart[wid & 1][qi + i * 16 + (lane >> 4) * 4 + q] = s;
        }
    __syncthreads();
    float rsum = 0.f;
    if (tid < 128) rsum = rowpart[0][tid] + rowpart[1][tid];
    red[tid] = rsum;
    __syncthreads();
    if (tid < 128) rmv[tid] = rsum * (1.f / 128.f);
    for (int s2 = 128; s2 > 0; s2 >>= 1) {
        if (tid < s2) red[tid] += red[tid + s2];
        __syncthreads();
    }
    if (tid == 0) gmsh = red[0] * (1.f / (128.f * 128.f));
    __syncthreads();

    const float gm = gmsh;
#pragma unroll
    for (int i = 0; i < 4; ++i)
#pragma unroll
        for (int j = 0; j < 4; ++j)
#pragma unroll
            for (int q = 0; q < 4; ++q) {
                const int row = qi + i * 16 + (lane >> 4) * 4 + q;
                const int col = qj + j * 16 + (lane & 15);
                acc[i][j][q] += gm - rmv[row] - rmv[col];
            }

    // ---- ||C||^2 ----
    {
        float nsq = 0.f;
#pragma unroll
        for (int i = 0; i < 4; ++i)
#pragma unroll
            for (int j = 0; j < 4; ++j)
#pragma unroll
                for (int q = 0; q < 4; ++q)
                    nsq = fmaf(acc[i][j][q], acc[i][j][q], nsq);
        __syncthreads();
        red[tid] = nsq;
        __syncthreads();
        for (int s2 = 128; s2 > 0; s2 >>= 1) {
            if (tid < s2) red[tid] += red[tid + s2];
            __syncthreads();
        }
        if (tid == 0) normsq[n] = red[0];
    }

    // ---- store centered C, fragment-permuted flat order ----
#pragma unroll
    for (int i = 0; i < 4; ++i)
#pragma unroll
        for (int j = 0; j < 4; ++j) {
            float* dst = Cp + (size_t)n * 16384 + ((wid * 16 + i * 4 + j) * 256 + lane * 4);
            *(f32x4*)dst = acc[i][j];
        }
}

// =====================================================================
// K2: hsic partials. grid = 16 m-tiles x 64 k-chunks (1024 blocks).
// part[kc][b][m] = sum over k-chunk of Cx[b][k]*Cy[m][k].
// =====================================================================
__global__ __launch_bounds__(256, 2)
void hsic_partial(const float* __restrict__ Cp, float* __restrict__ part)
{
    __shared__ float cx[32][260];     // +4 pad: b-rows spread over banks
    __shared__ float red2[256][16];

    const int tid = threadIdx.x;
    const int bx  = blockIdx.x;
    const int mt  = bx >> 6;          // 0..15
    const int kc  = bx & 63;          // 0..63
    const int k0  = kc * 256;

    // stage Cx chunk (32 x 256 f32)
#pragma unroll
    for (int i = 0; i < 8; ++i) {
        const int idx = i * 1024 + tid * 4;
        const int b = idx >> 8, k = idx & 255;
        *(float4*)&cx[b][k] = *(const float4*)&Cp[(size_t)b * 16384 + k0 + k];
    }
    __syncthreads();

    const int kq = tid >> 6;          // 0..3
    const int bg = (tid >> 3) & 7;    // 0..7  -> b = bg + bi*8
    const int mg = tid & 7;           // 0..7  -> m = mt*32 + mg*4 + mi
    const float* cyBase = Cp + (size_t)(BB + mt * 32 + mg * 4) * 16384 + k0 + kq * 64;

    float a[4][4];
#pragma unroll
    for (int bi = 0; bi < 4; ++bi)
#pragma unroll
        for (int mi = 0; mi < 4; ++mi) a[bi][mi] = 0.f;

    for (int kk = 0; kk < 16; ++kk) {
        float4 cy[4];
#pragma unroll
        for (int mi = 0; mi < 4; ++mi)
            cy[mi] = *(const float4*)(cyBase + (size_t)mi * 16384 + kk * 4);
        float4 cxv[4];
#pragma unroll
        for (int bi = 0; bi < 4; ++bi)
            cxv[bi] = *(const float4*)&cx[bg + bi * 8][kq * 64 + kk * 4];
#pragma unroll
        for (int bi = 0; bi < 4; ++bi)
#pragma unroll
            for (int mi = 0; mi < 4; ++mi) {
                a[bi][mi] = fmaf(cxv[bi].x, cy[mi].x, a[bi][mi]);
                a[bi][mi] = fmaf(cxv[bi].y, cy[mi].y, a[bi][mi]);
                a[bi][mi] = fmaf(cxv[bi].z, cy[mi].z, a[bi][mi]);
                a[bi][mi] = fmaf(cxv[bi].w, cy[mi].w, a[bi][mi]);
            }
    }

#pragma unroll
    for (int e = 0; e < 16; ++e) red2[tid][e] = a[e >> 2][e & 3];
    __syncthreads();
    if (tid < 64) {
#pragma unroll
        for (int e = 0; e < 16; ++e) {
            const float s = red2[tid][e] + red2[tid + 64][e] +
                            red2[tid + 128][e] + red2[tid + 192][e];
            const int bi = e >> 2, mi = e & 3;
            const int b = ((tid >> 3) & 7) + bi * 8;
            const int m = mt * 32 + (tid & 7) * 4 + mi;
            part[((size_t)kc * 32 + b) * 512 + m] = s;
        }
    }
}

// =====================================================================
// K3: combine partials, emit loss matrix + per-row argmax (first-occurrence)
// =====================================================================
__global__ __launch_bounds__(256)
void combine_loss(const float* __restrict__ part,
                  const float* __restrict__ normsq,
                  float* __restrict__ hsic,
                  int* __restrict__ ids,
                  float* __restrict__ out)
{
    __shared__ float rv[256];
    __shared__ int   ri[256];
    const int b = blockIdx.x;
    const int tid = threadIdx.x;
    const float vx = sqrtf(normsq[b]);

    float best = -INFINITY; int bm = 0;
    for (int m = tid; m < MM; m += 256) {
        float s = 0.f;
        for (int kc = 0; kc < 64; ++kc)
            s += part[((size_t)kc * 32 + b) * 512 + m];
        hsic[b * MM + m] = s;
        const float vy = sqrtf(normsq[BB + m]);
        const float loss = -logf(fabsf(s) / (vx * vy) + EPSF);
        out[1 + b * MM + m] = loss;
        if (loss > best) { best = loss; bm = m; }   // ascending m: strict > keeps earliest
    }
    rv[tid] = best; ri[tid] = bm;
    __syncthreads();
    for (int s2 = 128; s2 > 0; s2 >>= 1) {
        if (tid < s2) {
            if (rv[tid + s2] > rv[tid] ||
                (rv[tid + s2] == rv[tid] && ri[tid + s2] < ri[tid])) {
                rv[tid] = rv[tid + s2]; ri[tid] = ri[tid + s2];
            }
        }
        __syncthreads();
    }
    if (tid == 0) { ids[b] = ri[0]; out[1 + BB * MM + b] = (float)ri[0]; }
}

// =====================================================================
// K4: scalar loss via gather identity hsic2[b,c] = hsic[b, idx[c]]
// =====================================================================
__global__ __launch_bounds__(1024)
void scalar_loss(const float* __restrict__ hsic,
                 const float* __restrict__ normsq,
                 const int* __restrict__ ids,
                 float* __restrict__ out)
{
    __shared__ float red[1024];
    const int tid = threadIdx.x;
    const int b = tid >> 5, c = tid & 31;
    const int m = ids[c];
    red[tid] = fabsf(hsic[b * MM + m]) /
               (sqrtf(normsq[b]) * sqrtf(normsq[BB + m]));
    __syncthreads();
    for (int s = 512; s > 0; s >>= 1) {
        if (tid < s) red[tid] += red[tid + s];
        __syncthreads();
    }
    if (tid == 0) out[0] = -logf(red[0] * (1.f / 1024.f) + EPSF);
}

// =====================================================================
// ============== FALLBACK PATH (round-2, passing) =====================
// =====================================================================
#define OWS_CX      0
#define OWS_NSQX    524288
#define OWS_NSQY    524320
#define OWS_HSIC    524832

template<int FUSE>
__global__ __launch_bounds__(256, 2)
void gram_mfma(const float* __restrict__ Aall,
               float* __restrict__ Cout,
               float* __restrict__ normsq,
               const float* __restrict__ Cxp,
               float* __restrict__ hsic)
{
    __shared__ short8b planes[3][4][128];
    __shared__ float colpart[32][32];
    __shared__ float kmean[32];
    __shared__ float red[256];
    __shared__ float warr[BB * 4];

    const int tid  = threadIdx.x;
    const int lane = tid & 63;
    const int wid  = tid >> 6;
    const int qi   = (wid >> 1) * 64;
    const int qj   = (wid & 1) * 64;
    const int n    = blockIdx.x;
    const float* Amat = Aall + (size_t)n * LL * HH;

    const int rg = tid >> 3;
    const int kb = tid & 7;

    f32x4 acc[4][4];
#pragma unroll
    for (int i = 0; i < 4; ++i)
#pragma unroll
        for (int j = 0; j < 4; ++j) acc[i][j] = (f32x4){0.f, 0.f, 0.f, 0.f};

    uint2* P2 = (uint2*)planes;
    float4 v[4];
#pragma unroll
    for (int p = 0; p < 4; ++p)
        v[p] = *(const float4*)(Amat + (size_t)(rg + 32 * p) * HH + kb * 4);

    for (int t = 0; t < 16; ++t) {
        float4 vn[4];
        const int k0n = (t < 15) ? (t + 1) * 32 : 480;
#pragma unroll
        for (int p = 0; p < 4; ++p)
            vn[p] = *(const float4*)(Amat + (size_t)(rg + 32 * p) * HH + k0n + kb * 4);

        float4 cp;
        cp.x = v[0].x + v[1].x + v[2].x + v[3].x;
        cp.y = v[0].y + v[1].y + v[2].y + v[3].y;
        cp.z = v[0].z + v[1].z + v[2].z + v[3].z;
        cp.w = v[0].w + v[1].w + v[2].w + v[3].w;
        *(float4*)&colpart[rg][kb * 4] = cp;
        __syncthreads();
        if (tid < 32) {
            float s = 0.f;
#pragma unroll
            for (int g = 0; g < 32; ++g) s += colpart[g][tid];
            kmean[tid] = s * (1.f / LL);
        }
        __syncthreads();

        const float mu0 = kmean[kb * 4 + 0];
        const float mu1 = kmean[kb * 4 + 1];
        const float mu2 = kmean[kb * 4 + 2];
        const float mu3 = kmean[kb * 4 + 3];
#pragma unroll
        for (int p = 0; p < 4; ++p) {
            const int r = rg + 32 * p;
            const float c0 = v[p].x - mu0;
            const float c1 = v[p].y - mu1;
            const float c2 = v[p].z - mu2;
            const float c3 = v[p].w - mu3;
            const unsigned int h0 = __float_as_uint(c0) & 0xffff0000u;
            const unsigned int h1 = __float_as_uint(c1) & 0xffff0000u;
            const unsigned int h2 = __float_as_uint(c2) & 0xffff0000u;
            const unsigned int h3 = __float_as_uint(c3) & 0xffff0000u;
            const float r10 = c0 - __uint_as_float(h0);
            const float r11 = c1 - __uint_as_float(h1);
            const float r12 = c2 - __uint_as_float(h2);
            const float r13 = c3 - __uint_as_float(h3);
            const unsigned int m0 = __float_as_uint(r10) & 0xffff0000u;
            const unsigned int m1 = __float_as_uint(r11) & 0xffff0000u;
            const unsigned int m2 = __float_as_uint(r12) & 0xffff0000u;
            const unsigned int m3 = __float_as_uint(r13) & 0xffff0000u;
            const unsigned int l0 = __float_as_uint(r10 - __uint_as_float(m0));
            const unsigned int l1 = __float_as_uint(r11 - __uint_as_float(m1));
            const unsigned int l2 = __float_as_uint(r12 - __uint_as_float(m2));
            const unsigned int l3 = __float_as_uint(r13 - __uint_as_float(m3));
            uint2 w0, w1, w2;
            w0.x = (h0 >> 16) | h1;                  w0.y = (h2 >> 16) | h3;
            w1.x = (m0 >> 16) | m1;                  w1.y = (m2 >> 16) | m3;
            w2.x = (l0 >> 16) | (l1 & 0xffff0000u);  w2.y = (l2 >> 16) | (l3 & 0xffff0000u);
            const int u2 = ((kb >> 1) * 128 + r) * 2 + (kb & 1);
            P2[u2]        = w0;
            P2[u2 + 1024] = w1;
            P2[u2 + 2048] = w2;
        }
        __syncthreads();

        {
            const int s = lane >> 4, lr = lane & 15;
            short8b af0[4], af1[4], af2[4];
#pragma unroll
            for (int i = 0; i < 4; ++i) {
                const int r = qi + i * 16 + lr;
                af0[i] = planes[0][s][r];
                af1[i] = planes[1][s][r];
                af2[i] = planes[2][s][r];
            }
#pragma unroll
            for (int j = 0; j < 4; ++j) {
                const int r = qj + j * 16 + lr;
                const short8b b0 = planes[0][s][r];
                const short8b b1 = planes[1][s][r];
                const short8b b2 = planes[2][s][r];
#pragma unroll
                for (int i = 0; i < 4; ++i) {
                    acc[i][j] = __builtin_amdgcn_mfma_f32_16x16x32_bf16(af0[i], b0, acc[i][j], 0, 0, 0);
                    acc[i][j] = __builtin_amdgcn_mfma_f32_16x16x32_bf16(af0[i], b1, acc[i][j], 0, 0, 0);
                    acc[i][j] = __builtin_amdgcn_mfma_f32_16x16x32_bf16(af1[i], b0, acc[i][j], 0, 0, 0);
                    acc[i][j] = __builtin_amdgcn_mfma_f32_16x16x32_bf16(af1[i], b1, acc[i][j], 0, 0, 0);
                    acc[i][j] = __builtin_amdgcn_mfma_f32_16x16x32_bf16(af0[i], b2, acc[i][j], 0, 0, 0);
                    acc[i][j] = __builtin_amdgcn_mfma_f32_16x16x32_bf16(af2[i], b0, acc[i][j], 0, 0, 0);
                }
            }
        }
#pragma unroll
        for (int p = 0; p < 4; ++p) v[p] = vn[p];
    }

    {
        float nsq = 0.f;
#pragma unroll
        for (int i = 0; i < 4; ++i)
#pragma unroll
            for (int j = 0; j < 4; ++j)
#pragma unroll
                for (int q = 0; q < 4; ++q)
                    nsq = fmaf(acc[i][j][q], acc[i][j][q], nsq);
        red[tid] = nsq;
        __syncthreads();
        for (int s = 128; s > 0; s >>= 1) {
            if (tid < s) red[tid] += red[tid + s];
            __syncthreads();
        }
        if (tid == 0) normsq[n] = red[0];
    }

    if (FUSE == 0) {
#pragma unroll
        for (int i = 0; i < 4; ++i)
#pragma unroll
            for (int j = 0; j < 4; ++j) {
                const int t = i * 4 + j;
                float* dst = Cout + (((size_t)n * 4 + wid) * 16 + t) * 256 + lane * 4;
                *(f32x4*)dst = acc[i][j];
            }
    } else {
        for (int b = 0; b < BB; ++b) {
            const float* Cb = Cxp + ((size_t)b * 4 + wid) * 4096 + lane * 4;
            float p = 0.f;
#pragma unroll
            for (int t = 0; t < 16; ++t) {
                const f32x4 u = *(const f32x4*)(Cb + t * 256);
                const int i = t >> 2, j = t & 3;
                p = fmaf(u[0], acc[i][j][0], p);
                p = fmaf(u[1], acc[i][j][1], p);
                p = fmaf(u[2], acc[i][j][2], p);
                p = fmaf(u[3], acc[i][j][3], p);
            }
#pragma unroll
            for (int off = 32; off > 0; off >>= 1) p += __shfl_down(p, off, 64);
            if (lane == 0) warr[b * 4 + wid] = p;
        }
        __syncthreads();
        if (tid < BB) {
            hsic[(size_t)tid * MM + n] = warr[tid * 4] + warr[tid * 4 + 1] +
                                         warr[tid * 4 + 2] + warr[tid * 4 + 3];
        }
    }
}

__global__ __launch_bounds__(512)
void finalize_kernel(const float* __restrict__ normsqx,
                     const float* __restrict__ normsqy,
                     const float* __restrict__ hsic,
                     float* __restrict__ out)
{
    __shared__ float vx[BB];
    __shared__ float vy[MM];
    __shared__ int   ids[BB];
    __shared__ float rsum[512];

    const int tid = threadIdx.x;
    if (tid < BB) vx[tid] = sqrtf(normsqx[tid]);
    vy[tid] = sqrtf(normsqy[tid]);
    __syncthreads();

    for (int i = tid; i < BB * MM; i += 512) {
        const int b = i >> 9, m = i & 511;
        const float ratio = fabsf(hsic[i]) / (vx[b] * vy[m]);
        out[1 + i] = -logf(ratio + EPSF);
    }
    __syncthreads();

    const int wid = tid >> 6, lane = tid & 63;
    for (int b = wid; b < BB; b += 8) {
        float best = -INFINITY;
        int bm = 0;
        for (int m = lane; m < MM; m += 64) {
            const float ratio = fabsf(hsic[b * MM + m]) / (vx[b] * vy[m]);
            const float v = -logf(ratio + EPSF);
            if (v > best) { best = v; bm = m; }
        }
#pragma unroll
        for (int off = 32; off > 0; off >>= 1) {
            const float ov = __shfl_down(best, off, 64);
            const int   om = __shfl_down(bm, off, 64);
            if (ov > best || (ov == best && om < bm)) { best = ov; bm = om; }
        }
        if (lane == 0) {
            ids[b] = bm;
            out[1 + BB * MM + b] = (float)bm;
        }
    }
    __syncthreads();

    float s = 0.f;
    for (int i = tid; i < BB * BB; i += 512) {
        const int b = i >> 5, c = i & 31;
        const int m = ids[c];
        s += fabsf(hsic[(size_t)b * MM + m]) / (vx[b] * vy[m]);
    }
    rsum[tid] = s;
    __syncthreads();
    for (int t = 256; t > 0; t >>= 1) {
        if (tid < t) rsum[tid] += rsum[tid + t];
        __syncthreads();
    }
    if (tid == 0) out[0] = -logf(rsum[0] * (1.f / (BB * BB)) + EPSF);
}

// =====================================================================
extern "C" void kernel_launch(void* const* d_in, const int* in_sizes, int n_in,
                              void* d_out, int out_size, void* d_ws, size_t ws_size,
                              hipStream_t stream) {
    const float* x    = (const float*)d_in[0];
    const float* cent = (const float*)d_in[1];
    float* out = (float*)d_out;
    float* ws  = (float*)d_ws;

    if (ws_size >= NWS_BYTES) {
        float* Cp     = ws + NWS_CP;
        float* part   = ws + NWS_PART;
        float* normsq = ws + NWS_NSQ;
        float* hsic   = ws + NWS_HSIC;
        int*   ids    = (int*)(ws + NWS_IDS);

        gram_center_store<<<NM, 256, 0, stream>>>(x, cent, Cp, normsq);
        hsic_partial<<<1024, 256, 0, stream>>>(Cp, part);
        combine_loss<<<BB, 256, 0, stream>>>(part, normsq, hsic, ids, out);
        scalar_loss<<<1, 1024, 0, stream>>>(hsic, normsq, ids, out);
    } else {
        float* Cx      = ws + OWS_CX;
        float* normsqx = ws + OWS_NSQX;
        float* normsqy = ws + OWS_NSQY;
        float* hsic    = ws + OWS_HSIC;
        gram_mfma<0><<<BB, 256, 0, stream>>>(x, Cx, normsqx, nullptr, nullptr);
        gram_mfma<1><<<MM, 256, 0, stream>>>(cent, nullptr, normsqy, Cx, hsic);
        finalize_kernel<<<1, 512, 0, stream>>>(normsqx, normsqy, hsic, out);
    }
}

// Round 4
// 102.462 us; speedup vs baseline: 2.2601x; 1.1141x over previous
//
#include <hip/hip_runtime.h>
#include <math.h>

#define BB 32
#define LL 128
#define HH 512
#define MM 512
#define NM 544          // 32 x-matrices + 512 centroids
#define EPSF 1e-8f
#define CPLEN 9216      // 36 tiles * 256 floats (upper triangle, sqrt2-scaled offdiag)
#define NCH 36          // k-chunks of 256 in hsic_partial

typedef __attribute__((ext_vector_type(8))) short short8b;  // 8 bf16
typedef __attribute__((ext_vector_type(4))) float f32x4;

// ---------------- ws layout (floats) ----------------
//   Cp     [544][9216]    @ 0
//   part   [36][32][512]  @ 5013504
//   normsq [544]          @ 5603328
//   hsic   [32][512]      @ 5603872
//   ids    [32] (int)     @ 5620256
#define NWS_CP     0
#define NWS_PART   5013504
#define NWS_NSQ    5603328
#define NWS_HSIC   5603872
#define NWS_IDS    5620256

__device__ __forceinline__ float4 shflx1(float4 a) {
    float4 r;
    r.x = __shfl_xor(a.x, 1, 64);
    r.y = __shfl_xor(a.y, 1, 64);
    r.z = __shfl_xor(a.z, 1, 64);
    r.w = __shfl_xor(a.w, 1, 64);
    return r;
}

__device__ __forceinline__ unsigned pack2(unsigned lo, unsigned hi) {
    return (lo >> 16) | (hi & 0xffff0000u);
}

// exact 3-plane bf16 split of 8 floats (c = p0 + p1 + p2 to ~2^-24 rel)
__device__ __forceinline__ void split3(const float4 lo, const float4 hi,
                                       uint4& p0, uint4& p1, uint4& p2) {
    float c[8] = {lo.x, lo.y, lo.z, lo.w, hi.x, hi.y, hi.z, hi.w};
    unsigned h[8], m[8], l[8];
#pragma unroll
    for (int i = 0; i < 8; ++i) {
        h[i] = __float_as_uint(c[i]) & 0xffff0000u;
        const float r1 = c[i] - __uint_as_float(h[i]);
        m[i] = __float_as_uint(r1) & 0xffff0000u;
        l[i] = __float_as_uint(r1 - __uint_as_float(m[i]));
    }
    p0 = make_uint4(pack2(h[0],h[1]), pack2(h[2],h[3]), pack2(h[4],h[5]), pack2(h[6],h[7]));
    p1 = make_uint4(pack2(m[0],m[1]), pack2(m[2],m[3]), pack2(m[4],m[5]), pack2(m[6],m[7]));
    p2 = make_uint4(pack2(l[0],l[1]), pack2(l[2],l[3]), pack2(l[4],l[5]), pack2(l[6],l[7]));
}

__device__ __forceinline__ void mfma6(f32x4& d,
                                      short8b a0, short8b a1, short8b a2,
                                      short8b b0, short8b b1, short8b b2) {
    d = __builtin_amdgcn_mfma_f32_16x16x32_bf16(a0, b0, d, 0, 0, 0);
    d = __builtin_amdgcn_mfma_f32_16x16x32_bf16(a0, b1, d, 0, 0, 0);
    d = __builtin_amdgcn_mfma_f32_16x16x32_bf16(a1, b0, d, 0, 0, 0);
    d = __builtin_amdgcn_mfma_f32_16x16x32_bf16(a1, b1, d, 0, 0, 0);
    d = __builtin_amdgcn_mfma_f32_16x16x32_bf16(a0, b2, d, 0, 0, 0);
    d = __builtin_amdgcn_mfma_f32_16x16x32_bf16(a2, b0, d, 0, 0, 0);
}

// Wave W owns strips (W, 7-W): tiles (W, j) j=W..7 -> acc[j-W];
// (7-W, j) j=7-W..7 -> acc[8-W + j-(7-W)]. 9 tiles, 54 MFMA per k-tile.
template<int W>
__device__ __forceinline__ void do_step(f32x4 (&acc)[9],
                                        const short8b (*pl)[4][128],
                                        int lane) {
    const int s = lane >> 4, lr = lane & 15;
    short8b A0[3], A1[3];
#pragma unroll
    for (int p = 0; p < 3; ++p) {
        A0[p] = pl[p][s][W * 16 + lr];
        A1[p] = pl[p][s][(7 - W) * 16 + lr];
    }
#pragma unroll
    for (int j = W; j <= 7; ++j) {
        const short8b b0 = pl[0][s][j * 16 + lr];
        const short8b b1 = pl[1][s][j * 16 + lr];
        const short8b b2 = pl[2][s][j * 16 + lr];
        mfma6(acc[j - W], A0[0], A0[1], A0[2], b0, b1, b2);
        if (j >= 7 - W)
            mfma6(acc[(8 - W) + (j - (7 - W))], A1[0], A1[1], A1[2], b0, b1, b2);
    }
}

__device__ __forceinline__ float red16(float v) {
    v += __shfl_xor(v, 1, 64);
    v += __shfl_xor(v, 2, 64);
    v += __shfl_xor(v, 4, 64);
    v += __shfl_xor(v, 8, 64);
    return v;   // sum over the 16 lanes of the quarter-wave (cols)
}

// Accumulate row-parts (-> strip rows) and col-parts (-> tj rows) into Ssh128.
template<int W>
__device__ __forceinline__ void epi_sums(f32x4 (&acc)[9], float* Ssh128, int lane) {
    float rs0[4] = {0.f, 0.f, 0.f, 0.f};
    float rs1[4] = {0.f, 0.f, 0.f, 0.f};
#pragma unroll
    for (int j = W; j <= 7; ++j) {
        float cpj = 0.f;
        {
            const f32x4 a = acc[j - W];
#pragma unroll
            for (int q = 0; q < 4; ++q) rs0[q] += red16(a[q]);
            if (j > W) {
                float cl = a[0] + a[1] + a[2] + a[3];
                cl += __shfl_xor(cl, 16, 64);
                cl += __shfl_xor(cl, 32, 64);
                cpj += cl;
            }
        }
        if (j >= 7 - W) {
            const f32x4 a = acc[(8 - W) + (j - (7 - W))];
#pragma unroll
            for (int q = 0; q < 4; ++q) rs1[q] += red16(a[q]);
            if (j > 7 - W) {
                float cl = a[0] + a[1] + a[2] + a[3];
                cl += __shfl_xor(cl, 16, 64);
                cl += __shfl_xor(cl, 32, 64);
                cpj += cl;
            }
        }
        if (lane < 16) Ssh128[j * 16 + lane] += cpj;
    }
    if ((lane & 15) == 0) {
        const int g = lane >> 4;
#pragma unroll
        for (int q = 0; q < 4; ++q) {
            Ssh128[W * 16 + g * 4 + q]       += rs0[q];
            Ssh128[(7 - W) * 16 + g * 4 + q] += rs1[q];
        }
    }
}

// Center, sqrt2-scale offdiag, accumulate ||C||^2 partial, store tiles.
template<int W>
__device__ __forceinline__ float epi_store(f32x4 (&acc)[9], const float* rmv,
                                           float gm, int lane, float* dstBase) {
    const int g = lane >> 4, c = lane & 15;
    const float R2 = 1.41421356237309505f;
    float ri0[4], ri1[4];
#pragma unroll
    for (int q = 0; q < 4; ++q) {
        ri0[q] = rmv[W * 16 + g * 4 + q];
        ri1[q] = rmv[(7 - W) * 16 + g * 4 + q];
    }
    float nsq = 0.f;
#pragma unroll
    for (int j = W; j <= 7; ++j) {
        const float rj = rmv[j * 16 + c];
        {
            f32x4 a = acc[j - W];
#pragma unroll
            for (int q = 0; q < 4; ++q) {
                a[q] += gm - ri0[q] - rj;
                if (j > W) a[q] *= R2;
                nsq = fmaf(a[q], a[q], nsq);
            }
            const int t = W * 8 - W * (W - 1) / 2 + (j - W);
            *(f32x4*)(dstBase + t * 256 + lane * 4) = a;
        }
        if (j >= 7 - W) {
            f32x4 a = acc[(8 - W) + (j - (7 - W))];
#pragma unroll
            for (int q = 0; q < 4; ++q) {
                a[q] += gm - ri1[q] - rj;
                if (j > 7 - W) a[q] *= R2;
                nsq = fmaf(a[q], a[q], nsq);
            }
            const int ti = 7 - W;
            const int t = ti * 8 - ti * (ti - 1) / 2 + (j - ti);
            *(f32x4*)(dstBase + t * 256 + lane * 4) = a;
        }
    }
    return nsq;
}

// =====================================================================
// K1: symmetric centered Gram, upper-triangle tiles only. 544 blocks.
// =====================================================================
__global__ __launch_bounds__(256, 3)
void gram_sym(const float* __restrict__ x,
              const float* __restrict__ cent,
              float* __restrict__ Cp,
              float* __restrict__ normsq)
{
    __shared__ short8b planes[2][3][4][128];   // 48 KB, double-buffered
    __shared__ float Ssh[4][128];              // per-wave row-sum slices
    __shared__ float rmv[128];
    __shared__ float red[256];
    __shared__ float gmsh;

    const int tid  = threadIdx.x;
    const int lane = tid & 63;
    const int wid  = tid >> 6;
    const int n    = blockIdx.x;
    const float* Amat = (n < BB) ? (x + (size_t)n * LL * HH)
                                 : (cent + (size_t)(n - BB) * LL * HH);

    const int rg  = tid >> 3;     // 0..31
    const int kb  = tid & 7;      // k-quad
    const int odd = kb & 1;
    const int s   = kb >> 1;      // k-slot (8 floats)
    const int rowA = (odd ? 64 : 0) + rg;   // kept rows after pair exchange
    const int rowB = rowA + 32;

    f32x4 acc[9];
#pragma unroll
    for (int i = 0; i < 9; ++i) acc[i] = (f32x4){0.f, 0.f, 0.f, 0.f};

    float4 v[4];
#pragma unroll
    for (int p = 0; p < 4; ++p)
        v[p] = *(const float4*)(Amat + (size_t)(rg + 32 * p) * HH + kb * 4);

    for (int t = 0; t < 16; ++t) {
        const int pb = t & 1;
        // ---- pair exchange: thread ends with 2 rows x 8 consecutive k ----
        const float4 sA = odd ? v[0] : v[2];
        const float4 sB = odd ? v[1] : v[3];
        const float4 rA = shflx1(sA);
        const float4 rB = shflx1(sB);
        const float4 loA = odd ? rA : v[0];
        const float4 hiA = odd ? v[2] : rA;
        const float4 loB = odd ? rB : v[1];
        const float4 hiB = odd ? v[3] : rB;

        uint4 pA0, pA1, pA2, pB0, pB1, pB2;
        split3(loA, hiA, pA0, pA1, pA2);
        split3(loB, hiB, pB0, pB1, pB2);

        uint4* P4 = (uint4*)planes[pb];
        P4[(0 * 4 + s) * 128 + rowA] = pA0;
        P4[(1 * 4 + s) * 128 + rowA] = pA1;
        P4[(2 * 4 + s) * 128 + rowA] = pA2;
        P4[(0 * 4 + s) * 128 + rowB] = pB0;
        P4[(1 * 4 + s) * 128 + rowB] = pB1;
        P4[(2 * 4 + s) * 128 + rowB] = pB2;

        // ---- prefetch next k-tile (hidden under barrier + MFMA) ----
        float4 vn[4];
        const int k0n = (t < 15) ? (t + 1) * 32 : 480;
#pragma unroll
        for (int p = 0; p < 4; ++p)
            vn[p] = *(const float4*)(Amat + (size_t)(rg + 32 * p) * HH + k0n + kb * 4);

        __syncthreads();

        switch (wid) {
            case 0: do_step<0>(acc, planes[pb], lane); break;
            case 1: do_step<1>(acc, planes[pb], lane); break;
            case 2: do_step<2>(acc, planes[pb], lane); break;
            default: do_step<3>(acc, planes[pb], lane); break;
        }
#pragma unroll
        for (int p = 0; p < 4; ++p) v[p] = vn[p];
    }

    // ---- row sums of raw Gram (for double-centering) ----
    Ssh[wid][lane] = 0.f;
    Ssh[wid][lane + 64] = 0.f;
    switch (wid) {
        case 0: epi_sums<0>(acc, Ssh[0], lane); break;
        case 1: epi_sums<1>(acc, Ssh[1], lane); break;
        case 2: epi_sums<2>(acc, Ssh[2], lane); break;
        default: epi_sums<3>(acc, Ssh[3], lane); break;
    }
    __syncthreads();

    float Sv = 0.f;
    if (tid < 128) {
        Sv = Ssh[0][tid] + Ssh[1][tid] + Ssh[2][tid] + Ssh[3][tid];
        rmv[tid] = Sv * (1.f / 128.f);
    }
    red[tid] = (tid < 128) ? Sv : 0.f;
    __syncthreads();
    for (int s2 = 128; s2 > 0; s2 >>= 1) {
        if (tid < s2) red[tid] += red[tid + s2];
        __syncthreads();
    }
    if (tid == 0) gmsh = red[0] * (1.f / 16384.f);
    __syncthreads();
    const float gm = gmsh;

    // ---- center + scale + store; ||C||^2 ----
    float nsq;
    float* dstBase = Cp + (size_t)n * CPLEN;
    switch (wid) {
        case 0: nsq = epi_store<0>(acc, rmv, gm, lane, dstBase); break;
        case 1: nsq = epi_store<1>(acc, rmv, gm, lane, dstBase); break;
        case 2: nsq = epi_store<2>(acc, rmv, gm, lane, dstBase); break;
        default: nsq = epi_store<3>(acc, rmv, gm, lane, dstBase); break;
    }
    __syncthreads();
    red[tid] = nsq;
    __syncthreads();
    for (int s2 = 128; s2 > 0; s2 >>= 1) {
        if (tid < s2) red[tid] += red[tid + s2];
        __syncthreads();
    }
    if (tid == 0) normsq[n] = red[0];
}

// =====================================================================
// K2: hsic partials. grid = 16 m-tiles x 36 k-chunks (576 blocks).
// =====================================================================
__global__ __launch_bounds__(256, 2)
void hsic_partial(const float* __restrict__ Cp, float* __restrict__ part)
{
    __shared__ float cx[32][260];
    __shared__ float red2[256][16];

    const int tid = threadIdx.x;
    const int bx  = blockIdx.x;
    const int mt  = bx / NCH;
    const int kc  = bx % NCH;
    const int k0  = kc * 256;

#pragma unroll
    for (int i = 0; i < 8; ++i) {
        const int idx = i * 1024 + tid * 4;
        const int b = idx >> 8, k = idx & 255;
        *(float4*)&cx[b][k] = *(const float4*)&Cp[(size_t)b * CPLEN + k0 + k];
    }
    __syncthreads();

    const int kq = tid >> 6;
    const int bg = (tid >> 3) & 7;
    const int mg = tid & 7;
    const float* cyBase = Cp + (size_t)(BB + mt * 32 + mg * 4) * CPLEN + k0 + kq * 64;

    float a[4][4];
#pragma unroll
    for (int bi = 0; bi < 4; ++bi)
#pragma unroll
        for (int mi = 0; mi < 4; ++mi) a[bi][mi] = 0.f;

    for (int kk = 0; kk < 16; ++kk) {
        float4 cy[4];
#pragma unroll
        for (int mi = 0; mi < 4; ++mi)
            cy[mi] = *(const float4*)(cyBase + (size_t)mi * CPLEN + kk * 4);
        float4 cxv[4];
#pragma unroll
        for (int bi = 0; bi < 4; ++bi)
            cxv[bi] = *(const float4*)&cx[bg + bi * 8][kq * 64 + kk * 4];
#pragma unroll
        for (int bi = 0; bi < 4; ++bi)
#pragma unroll
            for (int mi = 0; mi < 4; ++mi) {
                a[bi][mi] = fmaf(cxv[bi].x, cy[mi].x, a[bi][mi]);
                a[bi][mi] = fmaf(cxv[bi].y, cy[mi].y, a[bi][mi]);
                a[bi][mi] = fmaf(cxv[bi].z, cy[mi].z, a[bi][mi]);
                a[bi][mi] = fmaf(cxv[bi].w, cy[mi].w, a[bi][mi]);
            }
    }

#pragma unroll
    for (int e = 0; e < 16; ++e) red2[tid][e] = a[e >> 2][e & 3];
    __syncthreads();
    if (tid < 64) {
#pragma unroll
        for (int e = 0; e < 16; ++e) {
            const float s = red2[tid][e] + red2[tid + 64][e] +
                            red2[tid + 128][e] + red2[tid + 192][e];
            const int bi = e >> 2, mi = e & 3;
            const int b = ((tid >> 3) & 7) + bi * 8;
            const int m = mt * 32 + (tid & 7) * 4 + mi;
            part[((size_t)kc * 32 + b) * 512 + m] = s;
        }
    }
}

// =====================================================================
// K3: combine partials, loss matrix + per-row argmax (first occurrence)
// =====================================================================
__global__ __launch_bounds__(256)
void combine_loss(const float* __restrict__ part,
                  const float* __restrict__ normsq,
                  float* __restrict__ hsic,
                  int* __restrict__ ids,
                  float* __restrict__ out)
{
    __shared__ float rv[256];
    __shared__ int   ri[256];
    const int b = blockIdx.x;
    const int tid = threadIdx.x;
    const float vx = sqrtf(normsq[b]);

    float best = -INFINITY; int bm = 0;
    for (int m = tid; m < MM; m += 256) {
        float s = 0.f;
        for (int kc = 0; kc < NCH; ++kc)
            s += part[((size_t)kc * 32 + b) * 512 + m];
        hsic[b * MM + m] = s;
        const float vy = sqrtf(normsq[BB + m]);
        const float loss = -logf(fabsf(s) / (vx * vy) + EPSF);
        out[1 + b * MM + m] = loss;
        if (loss > best) { best = loss; bm = m; }   // ascending m keeps earliest
    }
    rv[tid] = best; ri[tid] = bm;
    __syncthreads();
    for (int s2 = 128; s2 > 0; s2 >>= 1) {
        if (tid < s2) {
            if (rv[tid + s2] > rv[tid] ||
                (rv[tid + s2] == rv[tid] && ri[tid + s2] < ri[tid])) {
                rv[tid] = rv[tid + s2]; ri[tid] = ri[tid + s2];
            }
        }
        __syncthreads();
    }
    if (tid == 0) { ids[b] = ri[0]; out[1 + BB * MM + b] = (float)ri[0]; }
}

// =====================================================================
// K4: scalar loss via gather identity hsic2[b,c] = hsic[b, idx[c]]
// =====================================================================
__global__ __launch_bounds__(1024)
void scalar_loss(const float* __restrict__ hsic,
                 const float* __restrict__ normsq,
                 const int* __restrict__ ids,
                 float* __restrict__ out)
{
    __shared__ float red[1024];
    const int tid = threadIdx.x;
    const int b = tid >> 5, c = tid & 31;
    const int m = ids[c];
    red[tid] = fabsf(hsic[b * MM + m]) /
               (sqrtf(normsq[b]) * sqrtf(normsq[BB + m]));
    __syncthreads();
    for (int s = 512; s > 0; s >>= 1) {
        if (tid < s) red[tid] += red[tid + s];
        __syncthreads();
    }
    if (tid == 0) out[0] = -logf(red[0] * (1.f / 1024.f) + EPSF);
}

// =====================================================================
extern "C" void kernel_launch(void* const* d_in, const int* in_sizes, int n_in,
                              void* d_out, int out_size, void* d_ws, size_t ws_size,
                              hipStream_t stream) {
    const float* x    = (const float*)d_in[0];   // (32,128,512)
    const float* cent = (const float*)d_in[1];   // (512, 128*512)
    float* out = (float*)d_out;
    float* ws  = (float*)d_ws;

    float* Cp     = ws + NWS_CP;
    float* part   = ws + NWS_PART;
    float* normsq = ws + NWS_NSQ;
    float* hsic   = ws + NWS_HSIC;
    int*   ids    = (int*)(ws + NWS_IDS);

    gram_sym<<<NM, 256, 0, stream>>>(x, cent, Cp, normsq);
    hsic_partial<<<16 * NCH, 256, 0, stream>>>(Cp, part);
    combine_loss<<<BB, 256, 0, stream>>>(part, normsq, hsic, ids, out);
    scalar_loss<<<1, 1024, 0, stream>>>(hsic, normsq, ids, out);
}

// Round 5
// 89.422 us; speedup vs baseline: 2.5897x; 1.1458x over previous
//
#include <hip/hip_runtime.h>
#include <math.h>

#define BB 32
#define LL 128
#define HH 512
#define MM 512
#define NM 544          // 32 x-matrices + 512 centroids
#define EPSF 1e-8f
#define CPLEN 10240     // 10 upper 32x32 tiles * 1024 floats (offdiag pre-scaled by sqrt2)
#define NCH 40          // k-chunks of 256 floats

typedef __attribute__((ext_vector_type(8))) short short8b;   // 8 bf16
typedef __attribute__((ext_vector_type(4))) float f32x4;
typedef __attribute__((ext_vector_type(16))) float f32x16;

// ---------------- ws layout (floats) ----------------
//   Cp     [544][10240]   @ 0
//   part   [40][32][512]  @ 5570560
//   normsq [544]          @ 6225920
//   hsic   [32][512]      @ 6226464
//   ids    [32] (int)     @ 6242848
#define NWS_CP    0
#define NWS_PART  5570560
#define NWS_NSQ   6225920
#define NWS_HSIC  6226464
#define NWS_IDS   6242848

__device__ __forceinline__ unsigned pack2(unsigned lo, unsigned hi) {
    return (lo >> 16) | (hi & 0xffff0000u);
}

// exact 3-plane bf16 split of 8 floats (c = p0+p1+p2 to ~2^-24 rel)
__device__ __forceinline__ void split3(const float4 lo, const float4 hi,
                                       uint4& p0, uint4& p1, uint4& p2) {
    float c[8] = {lo.x, lo.y, lo.z, lo.w, hi.x, hi.y, hi.z, hi.w};
    unsigned h[8], m[8], l[8];
#pragma unroll
    for (int i = 0; i < 8; ++i) {
        h[i] = __float_as_uint(c[i]) & 0xffff0000u;
        const float r1 = c[i] - __uint_as_float(h[i]);
        m[i] = __float_as_uint(r1) & 0xffff0000u;
        l[i] = __float_as_uint(r1 - __uint_as_float(m[i]));
    }
    p0 = make_uint4(pack2(h[0],h[1]), pack2(h[2],h[3]), pack2(h[4],h[5]), pack2(h[6],h[7]));
    p1 = make_uint4(pack2(m[0],m[1]), pack2(m[2],m[3]), pack2(m[4],m[5]), pack2(m[6],m[7]));
    p2 = make_uint4(pack2(l[0],l[1]), pack2(l[2],l[3]), pack2(l[4],l[5]), pack2(l[6],l[7]));
}

// 6 significant plane-products: hh, hm, mh, mm, hl, lh
__device__ __forceinline__ f32x16 mfma6(f32x16 d, const short8b a[3], const short8b b[3]) {
    d = __builtin_amdgcn_mfma_f32_32x32x16_bf16(a[0], b[0], d, 0, 0, 0);
    d = __builtin_amdgcn_mfma_f32_32x32x16_bf16(a[0], b[1], d, 0, 0, 0);
    d = __builtin_amdgcn_mfma_f32_32x32x16_bf16(a[1], b[0], d, 0, 0, 0);
    d = __builtin_amdgcn_mfma_f32_32x32x16_bf16(a[1], b[1], d, 0, 0, 0);
    d = __builtin_amdgcn_mfma_f32_32x32x16_bf16(a[0], b[2], d, 0, 0, 0);
    d = __builtin_amdgcn_mfma_f32_32x32x16_bf16(a[2], b[0], d, 0, 0, 0);
    return d;
}

// load one strip's 3-plane fragment: lane -> row strip*32+(lane&31), k-octet lane>>5
__device__ __forceinline__ void ldstrip(const uint4* P, int strip, int lane, short8b f[3]) {
    const int s = lane >> 5;
    const int r = strip * 32 + (lane & 31);
#pragma unroll
    for (int p = 0; p < 3; ++p) {
        uint4 u = P[(p * 2 + s) * 128 + r];
        f[p] = *(const short8b*)&u;
    }
}

// row sums (-> strip i) and, for offdiag, col sums (-> strip j) of raw tile
__device__ __forceinline__ void tile_sums(f32x16 a, float* S, int i, int j,
                                          bool offd, int lane) {
    const int hi = lane >> 5;
    float rs[16];
#pragma unroll
    for (int q = 0; q < 16; ++q) {
        float s = a[q];
        s += __shfl_xor(s, 1, 64);
        s += __shfl_xor(s, 2, 64);
        s += __shfl_xor(s, 4, 64);
        s += __shfl_xor(s, 8, 64);
        s += __shfl_xor(s, 16, 64);
        rs[q] = s;
    }
    if ((lane & 31) == 0) {
#pragma unroll
        for (int q = 0; q < 16; ++q)
            S[i * 32 + (q & 3) + 8 * (q >> 2) + 4 * hi] += rs[q];
    }
    if (offd) {
        float cs = 0.f;
#pragma unroll
        for (int q = 0; q < 16; ++q) cs += a[q];
        cs += __shfl_xor(cs, 32, 64);
        if (lane < 32) S[j * 32 + lane] += cs;
    }
}

// center + scale + store one tile; returns ||.||^2 partial
__device__ __forceinline__ float tile_fin(f32x16 a, const float* rmv, float gm,
                                          bool offd, int i, int j,
                                          float* dst, int lane) {
    const int hi = lane >> 5, col = lane & 31;
    const float cj = rmv[j * 32 + col];
    const float sc = offd ? 1.41421356237309505f : 1.f;
    float nsq = 0.f;
#pragma unroll
    for (int c = 0; c < 4; ++c) {
        const float4 ri = *(const float4*)&rmv[i * 32 + c * 8 + hi * 4];
        const float riq[4] = {ri.x, ri.y, ri.z, ri.w};
        f32x4 o;
#pragma unroll
        for (int q = 0; q < 4; ++q) {
            float vq = (a[c * 4 + q] + gm - riq[q] - cj) * sc;
            nsq = fmaf(vq, vq, nsq);
            o[q] = vq;
        }
        *(f32x4*)(dst + (c * 2 + hi) * 128 + col * 4) = o;
    }
    return nsq;
}

// =====================================================================
// K1: symmetric centered Gram, upper 32x32 tiles via mfma_32x32x16_bf16.
// Tile->wave: W0:(0,3),(1,3),(2,3)  W1:(3,3),(0,2),(1,2)  W2:(2,2),(0,1)
//             W3:(0,0),(1,1).   544 blocks x 256 threads.
// =====================================================================
__global__ __launch_bounds__(256, 4)
void gram_sym2(const float* __restrict__ x,
               const float* __restrict__ cent,
               float* __restrict__ Cp,
               float* __restrict__ normsq)
{
    __shared__ uint4 planes[2][3][2][128];   // 24 KB double-buffered
    __shared__ float Ssh[4][128];
    __shared__ float rmv[128];
    __shared__ float red[256];
    __shared__ float gmsh;

    const int tid  = threadIdx.x;
    const int lane = tid & 63;
    const int wid  = tid >> 6;
    const int n    = blockIdx.x;
    const float* Amat = (n < BB) ? (x + (size_t)n * LL * HH)
                                 : (cent + (size_t)(n - BB) * LL * HH);

    const int srow  = tid >> 1;   // staging row 0..127
    const int shalf = tid & 1;    // k-octet within k-16

    f32x16 a0, a1, a2;
#pragma unroll
    for (int q = 0; q < 16; ++q) { a0[q] = 0.f; a1[q] = 0.f; a2[q] = 0.f; }

    float4 v0 = *(const float4*)(Amat + (size_t)srow * HH + shalf * 8);
    float4 v1 = *(const float4*)(Amat + (size_t)srow * HH + shalf * 8 + 4);

    for (int t = 0; t < 32; ++t) {
        const int pb = t & 1;
        uint4 p0, p1, p2;
        split3(v0, v1, p0, p1, p2);
        uint4* P = &planes[pb][0][0][0];
        const int wbase = shalf * 128 + srow;
        P[0 * 256 + wbase] = p0;
        P[1 * 256 + wbase] = p1;
        P[2 * 256 + wbase] = p2;

        const int kn = (t < 31) ? (t + 1) * 16 : 496;   // redundant last reload
        v0 = *(const float4*)(Amat + (size_t)srow * HH + kn + shalf * 8);
        v1 = *(const float4*)(Amat + (size_t)srow * HH + kn + shalf * 8 + 4);

        __syncthreads();

        const uint4* Pr = &planes[pb][0][0][0];
        short8b fa[3], fb[3];
        if (wid == 0) {
            ldstrip(Pr, 3, lane, fb);
            ldstrip(Pr, 0, lane, fa); a0 = mfma6(a0, fa, fb);
            ldstrip(Pr, 1, lane, fa); a1 = mfma6(a1, fa, fb);
            ldstrip(Pr, 2, lane, fa); a2 = mfma6(a2, fa, fb);
        } else if (wid == 1) {
            ldstrip(Pr, 3, lane, fa); a0 = mfma6(a0, fa, fa);
            ldstrip(Pr, 2, lane, fb);
            ldstrip(Pr, 0, lane, fa); a1 = mfma6(a1, fa, fb);
            ldstrip(Pr, 1, lane, fa); a2 = mfma6(a2, fa, fb);
        } else if (wid == 2) {
            ldstrip(Pr, 2, lane, fa); a0 = mfma6(a0, fa, fa);
            ldstrip(Pr, 0, lane, fa);
            ldstrip(Pr, 1, lane, fb); a1 = mfma6(a1, fa, fb);
        } else {
            ldstrip(Pr, 0, lane, fa); a0 = mfma6(a0, fa, fa);
            ldstrip(Pr, 1, lane, fa); a1 = mfma6(a1, fa, fa);
        }
    }

    // ---- raw-Gram row sums for double-centering ----
    Ssh[wid][lane] = 0.f;
    Ssh[wid][lane + 64] = 0.f;
    if (wid == 0) {
        tile_sums(a0, Ssh[0], 0, 3, true, lane);
        tile_sums(a1, Ssh[0], 1, 3, true, lane);
        tile_sums(a2, Ssh[0], 2, 3, true, lane);
    } else if (wid == 1) {
        tile_sums(a0, Ssh[1], 3, 3, false, lane);
        tile_sums(a1, Ssh[1], 0, 2, true, lane);
        tile_sums(a2, Ssh[1], 1, 2, true, lane);
    } else if (wid == 2) {
        tile_sums(a0, Ssh[2], 2, 2, false, lane);
        tile_sums(a1, Ssh[2], 0, 1, true, lane);
    } else {
        tile_sums(a0, Ssh[3], 0, 0, false, lane);
        tile_sums(a1, Ssh[3], 1, 1, false, lane);
    }
    __syncthreads();

    float Sv = 0.f;
    if (tid < 128) {
        Sv = Ssh[0][tid] + Ssh[1][tid] + Ssh[2][tid] + Ssh[3][tid];
        rmv[tid] = Sv * (1.f / 128.f);
    }
    red[tid] = (tid < 128) ? Sv : 0.f;
    __syncthreads();
    for (int s2 = 128; s2 > 0; s2 >>= 1) {
        if (tid < s2) red[tid] += red[tid + s2];
        __syncthreads();
    }
    if (tid == 0) gmsh = red[0] * (1.f / 16384.f);
    __syncthreads();
    const float gm = gmsh;

    // ---- center + sqrt2-scale + store; ||C||^2 ----
    float nsq = 0.f;
    float* dst = Cp + (size_t)n * CPLEN;
    if (wid == 0) {
        nsq += tile_fin(a0, rmv, gm, true, 0, 3, dst + 3 * 1024, lane);
        nsq += tile_fin(a1, rmv, gm, true, 1, 3, dst + 6 * 1024, lane);
        nsq += tile_fin(a2, rmv, gm, true, 2, 3, dst + 8 * 1024, lane);
    } else if (wid == 1) {
        nsq += tile_fin(a0, rmv, gm, false, 3, 3, dst + 9 * 1024, lane);
        nsq += tile_fin(a1, rmv, gm, true, 0, 2, dst + 2 * 1024, lane);
        nsq += tile_fin(a2, rmv, gm, true, 1, 2, dst + 5 * 1024, lane);
    } else if (wid == 2) {
        nsq += tile_fin(a0, rmv, gm, false, 2, 2, dst + 7 * 1024, lane);
        nsq += tile_fin(a1, rmv, gm, true, 0, 1, dst + 1 * 1024, lane);
    } else {
        nsq += tile_fin(a0, rmv, gm, false, 0, 0, dst + 0 * 1024, lane);
        nsq += tile_fin(a1, rmv, gm, false, 1, 1, dst + 4 * 1024, lane);
    }
    __syncthreads();
    red[tid] = nsq;
    __syncthreads();
    for (int s2 = 128; s2 > 0; s2 >>= 1) {
        if (tid < s2) red[tid] += red[tid + s2];
        __syncthreads();
    }
    if (tid == 0) normsq[n] = red[0];
}

// =====================================================================
// K2: hsic partials. grid = 16 m-tiles x 40 k-chunks (640 blocks).
// =====================================================================
__global__ __launch_bounds__(256, 2)
void hsic_partial(const float* __restrict__ Cp, float* __restrict__ part)
{
    __shared__ float cx[32][260];
    __shared__ float red2[256][16];

    const int tid = threadIdx.x;
    const int bx  = blockIdx.x;
    const int mt  = bx / NCH;
    const int kc  = bx % NCH;
    const int k0  = kc * 256;

#pragma unroll
    for (int i = 0; i < 8; ++i) {
        const int idx = i * 1024 + tid * 4;
        const int b = idx >> 8, k = idx & 255;
        *(float4*)&cx[b][k] = *(const float4*)&Cp[(size_t)b * CPLEN + k0 + k];
    }
    __syncthreads();

    const int kq = tid >> 6;
    const int bg = (tid >> 3) & 7;
    const int mg = tid & 7;
    const float* cyBase = Cp + (size_t)(BB + mt * 32 + mg * 4) * CPLEN + k0 + kq * 64;

    float a[4][4];
#pragma unroll
    for (int bi = 0; bi < 4; ++bi)
#pragma unroll
        for (int mi = 0; mi < 4; ++mi) a[bi][mi] = 0.f;

    for (int kk = 0; kk < 16; ++kk) {
        float4 cy[4];
#pragma unroll
        for (int mi = 0; mi < 4; ++mi)
            cy[mi] = *(const float4*)(cyBase + (size_t)mi * CPLEN + kk * 4);
        float4 cxv[4];
#pragma unroll
        for (int bi = 0; bi < 4; ++bi)
            cxv[bi] = *(const float4*)&cx[bg + bi * 8][kq * 64 + kk * 4];
#pragma unroll
        for (int bi = 0; bi < 4; ++bi)
#pragma unroll
            for (int mi = 0; mi < 4; ++mi) {
                a[bi][mi] = fmaf(cxv[bi].x, cy[mi].x, a[bi][mi]);
                a[bi][mi] = fmaf(cxv[bi].y, cy[mi].y, a[bi][mi]);
                a[bi][mi] = fmaf(cxv[bi].z, cy[mi].z, a[bi][mi]);
                a[bi][mi] = fmaf(cxv[bi].w, cy[mi].w, a[bi][mi]);
            }
    }

#pragma unroll
    for (int e = 0; e < 16; ++e) red2[tid][e] = a[e >> 2][e & 3];
    __syncthreads();
    if (tid < 64) {
#pragma unroll
        for (int e = 0; e < 16; ++e) {
            const float s = red2[tid][e] + red2[tid + 64][e] +
                            red2[tid + 128][e] + red2[tid + 192][e];
            const int bi = e >> 2, mi = e & 3;
            const int b = ((tid >> 3) & 7) + bi * 8;
            const int m = mt * 32 + (tid & 7) * 4 + mi;
            part[((size_t)kc * 32 + b) * 512 + m] = s;
        }
    }
}

// =====================================================================
// K3: combine partials, loss matrix + per-row argmax (first occurrence)
// =====================================================================
__global__ __launch_bounds__(256)
void combine_loss(const float* __restrict__ part,
                  const float* __restrict__ normsq,
                  float* __restrict__ hsic,
                  int* __restrict__ ids,
                  float* __restrict__ out)
{
    __shared__ float rv[256];
    __shared__ int   ri[256];
    const int b = blockIdx.x;
    const int tid = threadIdx.x;
    const float vx = sqrtf(normsq[b]);

    float best = -INFINITY; int bm = 0;
    for (int m = tid; m < MM; m += 256) {
        float s = 0.f;
        for (int kc = 0; kc < NCH; ++kc)
            s += part[((size_t)kc * 32 + b) * 512 + m];
        hsic[b * MM + m] = s;
        const float vy = sqrtf(normsq[BB + m]);
        const float loss = -logf(fabsf(s) / (vx * vy) + EPSF);
        out[1 + b * MM + m] = loss;
        if (loss > best) { best = loss; bm = m; }   // ascending m keeps earliest
    }
    rv[tid] = best; ri[tid] = bm;
    __syncthreads();
    for (int s2 = 128; s2 > 0; s2 >>= 1) {
        if (tid < s2) {
            if (rv[tid + s2] > rv[tid] ||
                (rv[tid + s2] == rv[tid] && ri[tid + s2] < ri[tid])) {
                rv[tid] = rv[tid + s2]; ri[tid] = ri[tid + s2];
            }
        }
        __syncthreads();
    }
    if (tid == 0) { ids[b] = ri[0]; out[1 + BB * MM + b] = (float)ri[0]; }
}

// =====================================================================
// K4: scalar loss via gather identity hsic2[b,c] = hsic[b, idx[c]]
// =====================================================================
__global__ __launch_bounds__(1024)
void scalar_loss(const float* __restrict__ hsic,
                 const float* __restrict__ normsq,
                 const int* __restrict__ ids,
                 float* __restrict__ out)
{
    __shared__ float red[1024];
    const int tid = threadIdx.x;
    const int b = tid >> 5, c = tid & 31;
    const int m = ids[c];
    red[tid] = fabsf(hsic[b * MM + m]) /
               (sqrtf(normsq[b]) * sqrtf(normsq[BB + m]));
    __syncthreads();
    for (int s = 512; s > 0; s >>= 1) {
        if (tid < s) red[tid] += red[tid + s];
        __syncthreads();
    }
    if (tid == 0) out[0] = -logf(red[0] * (1.f / 1024.f) + EPSF);
}

// =====================================================================
extern "C" void kernel_launch(void* const* d_in, const int* in_sizes, int n_in,
                              void* d_out, int out_size, void* d_ws, size_t ws_size,
                              hipStream_t stream) {
    const float* x    = (const float*)d_in[0];   // (32,128,512)
    const float* cent = (const float*)d_in[1];   // (512, 128*512)
    float* out = (float*)d_out;
    float* ws  = (float*)d_ws;

    float* Cp     = ws + NWS_CP;
    float* part   = ws + NWS_PART;
    float* normsq = ws + NWS_NSQ;
    float* hsic   = ws + NWS_HSIC;
    int*   ids    = (int*)(ws + NWS_IDS);

    gram_sym2<<<NM, 256, 0, stream>>>(x, cent, Cp, normsq);
    hsic_partial<<<16 * NCH, 256, 0, stream>>>(Cp, part);
    combine_loss<<<BB, 256, 0, stream>>>(part, normsq, hsic, ids, out);
    scalar_loss<<<1, 1024, 0, stream>>>(hsic, normsq, ids, out);
}